// Round 5
// baseline (981.745 us; speedup 1.0000x reference)
//
#include <hip/hip_runtime.h>

#define DD 48
#define HW (48 * 48)
#define NV (48 * 48 * 48)   // 110592 voxels
#define COUT 32

// deform tile geometry
#define TD 4
#define TH 8
#define TW 8
#define RD (TD + 4)         // 8   (halo +-2)
#define RH (TH + 4)         // 12
#define RW (TW + 4)         // 12
#define REGN (RD * RH * RW) // 1152 floats per channel
#define NCH 8               // channels staged per chunk

typedef _Float16 h16;

// ---------------------------------------------------------------------------
// Weight transpose: wt[co][ci][tap] -> wT[tap][ci][co]  (co contiguous so the
// wave-uniform scalar loads in the conv kernels hit 1-2 scalar-cache lines).
// ---------------------------------------------------------------------------
__global__ __launch_bounds__(256) void transpose_w_kernel(
    const float* __restrict__ wt, float* __restrict__ wT, int COUTN, int CIN)
{
    const int i = blockIdx.x * 256 + threadIdx.x;
    const int total = COUTN * CIN * 27;
    if (i >= total) return;
    const int co = i / (CIN * 27);
    const int r = i % (CIN * 27);
    const int ci = r / 27;
    const int tap = r % 27;
    wT[(tap * CIN + ci) * COUTN + co] = wt[i];
}

// ---------------------------------------------------------------------------
// 3x3x3 SAME conv (zero pad), all 81 offset channels in ONE pass (x read once;
// 81 FMAs per load hide latency). Output fp16.
// ---------------------------------------------------------------------------
template <int CIN>
__global__ __launch_bounds__(256) void conv3_off_kernel(
    const float* __restrict__ x, const float* __restrict__ wT,
    const float* __restrict__ bias, h16* __restrict__ out)
{
    const int v = blockIdx.x * 256 + threadIdx.x;
    const int d = v / HW;
    const int rem = v % HW;
    const int h = rem / DD;
    const int wv = rem % DD;

    float acc[81];
#pragma unroll
    for (int i = 0; i < 81; ++i) acc[i] = bias[i];

    int tap = 0;
    for (int dz = -1; dz <= 1; ++dz)
    for (int dy = -1; dy <= 1; ++dy)
    for (int dx = -1; dx <= 1; ++dx, ++tap) {
        const int zd = d + dz, zh = h + dy, zw = wv + dx;
        const bool ok = ((unsigned)zd < 48u) & ((unsigned)zh < 48u) & ((unsigned)zw < 48u);
        if (ok) {
            const int base = (zd * DD + zh) * DD + zw;
            const float* wrow = wT + (tap * CIN) * 81;
            for (int ci = 0; ci < CIN; ++ci) {
                const float xv = x[ci * NV + base];
                const float* wp = wrow + ci * 81;
#pragma unroll
                for (int i = 0; i < 81; ++i)
                    acc[i] += xv * wp[i];
            }
        }
    }
#pragma unroll
    for (int i = 0; i < 81; ++i) out[i * NV + v] = (h16)acc[i];
}

// ---------------------------------------------------------------------------
// Deformable conv, LDS-tiled. Key trick: when a sample coordinate clamps,
// its trilinear fraction is exactly 0, so the +1-neighbor coefficient is 0.
// Hence the LDS path reads all 8 corners at FIXED offsets {0,1,RW,RW+1,
// RH*RW,...} from one base -> compiler merges to ds_read2_b32 (half the LDS
// issue slots). Staged halo values are clamp-valid floats, so the unused
// neighbors are finite and zero-weighted.
// ---------------------------------------------------------------------------
template <int CIN>
__global__ __launch_bounds__(256) void deform_tile_kernel(
    const float* __restrict__ x, const h16* __restrict__ off,
    const float* __restrict__ wD, float* __restrict__ part)
{
    __shared__ float reg[NCH][REGN];   // 36864 B

    const int t = threadIdx.x;
    const int bx = blockIdx.x;               // 432 tiles
    const int tilew = bx % 6;
    const int tileh = (bx / 6) % 6;
    const int tiled = bx / 36;               // 0..11
    const int chunk = blockIdx.y;
    const int c0 = chunk * NCH;

    const int tz = t >> 6, ty = (t >> 3) & 7, tx = t & 7;
    const int d  = tiled * TD + tz;
    const int hh = tileh * TH + ty;
    const int ww = tilew * TW + tx;
    const int v  = (d * DD + hh) * DD + ww;

    const int dlo = tiled * TD - 2;
    const int hlo = tileh * TH - 2;
    const int wlo = tilew * TW - 2;

    // ---- stage x region for NCH channels (halo clamped to volume) ----
    for (int i = t; i < NCH * REGN; i += 256) {
        const int ci = i / REGN;
        const int r  = i % REGN;
        const int rz = r / (RH * RW);
        const int rr = r % (RH * RW);
        const int ry = rr / RW, rx = rr % RW;
        const int gz = min(max(dlo + rz, 0), 47);
        const int gy = min(max(hlo + ry, 0), 47);
        const int gx = min(max(wlo + rx, 0), 47);
        reg[ci][r] = x[(c0 + ci) * NV + (gz * DD + gy) * DD + gx];
    }
    __syncthreads();

    float acc[COUT];
#pragma unroll
    for (int i = 0; i < COUT; ++i) acc[i] = 0.0f;

    for (int k = 0; k < 27; ++k) {
        const int dz = k / 9 - 1;
        const int dy = (k / 3) % 3 - 1;
        const int dx = k % 3 - 1;

        const float od = (float)off[(0 * 27 + k) * NV + v];
        const float oh = (float)off[(1 * 27 + k) * NV + v];
        const float ow = (float)off[(2 * 27 + k) * NV + v];

        const float pd = fminf(fmaxf((float)(d + dz) + od, 0.0f), 47.0f);
        const float ph = fminf(fmaxf((float)(hh + dy) + oh, 0.0f), 47.0f);
        const float pw = fminf(fmaxf((float)(ww + dx) + ow, 0.0f), 47.0f);

        const float d0f = floorf(pd), h0f = floorf(ph), w0f = floorf(pw);
        const float fd = pd - d0f, fh = ph - h0f, fw = pw - w0f;
        const int d0 = (int)d0f, h0 = (int)h0f, w0 = (int)w0f;

        const float gd = 1.0f - fd, gh = 1.0f - fh, gw = 1.0f - fw;
        const float c000 = gd * gh * gw, c001 = gd * gh * fw;
        const float c010 = gd * fh * gw, c011 = gd * fh * fw;
        const float c100 = fd * gh * gw, c101 = fd * gh * fw;
        const float c110 = fd * fh * gw, c111 = fd * fh * fw;

        const float* wrow = wD + (k * CIN + c0) * COUT;

        const int ld = d0 - dlo, lh = h0 - hlo, lw = w0 - wlo;
        // fixed-offset reads need ld+1/lh+1/lw+1 in range
        const bool inreg = (ld >= 0) & (ld <= RD - 2)
                         & (lh >= 0) & (lh <= RH - 2)
                         & (lw >= 0) & (lw <= RW - 2);

        if (inreg) {
            const int base = (ld * RH + lh) * RW + lw;
#pragma unroll
            for (int ci = 0; ci < NCH; ++ci) {
                const float* xc = &reg[ci][base];
                const float v000 = xc[0],            v001 = xc[1];
                const float v010 = xc[RW],           v011 = xc[RW + 1];
                const float v100 = xc[RH * RW],      v101 = xc[RH * RW + 1];
                const float v110 = xc[RH * RW + RW], v111 = xc[RH * RW + RW + 1];
                const float val = v000 * c000 + v001 * c001
                                + v010 * c010 + v011 * c011
                                + v100 * c100 + v101 * c101
                                + v110 * c110 + v111 * c111;
                const float* wp = wrow + ci * COUT;
#pragma unroll
                for (int co = 0; co < COUT; ++co)
                    acc[co] += val * wp[co];
            }
        } else {
            const int dst = (d0 < 47) ? 1 : 0;
            const int hst = (h0 < 47) ? 1 : 0;
            const int wst = (w0 < 47) ? 1 : 0;
            const int i000 = (d0 * DD + h0) * DD + w0;
            const int sd = dst ? HW : 0, sh = hst ? DD : 0, sw = wst;
#pragma unroll
            for (int ci = 0; ci < NCH; ++ci) {
                const float* xc = x + (c0 + ci) * NV + i000;
                const float val = xc[0]       * c000 + xc[sw]           * c001
                                + xc[sh]      * c010 + xc[sh + sw]      * c011
                                + xc[sd]      * c100 + xc[sd + sw]      * c101
                                + xc[sd + sh] * c110 + xc[sd + sh + sw] * c111;
                const float* wp = wrow + ci * COUT;
#pragma unroll
                for (int co = 0; co < COUT; ++co)
                    acc[co] += val * wp[co];
            }
        }
    }

#pragma unroll
    for (int co = 0; co < COUT; ++co)
        part[(chunk * COUT + co) * NV + v] = acc[co];
}

// Sum NC split-K partials (float4).
template <int NC>
__global__ __launch_bounds__(256) void reduceN_kernel(
    const float* __restrict__ part, float* __restrict__ y)
{
    const int i = blockIdx.x * 256 + threadIdx.x;   // float4 index
    const int stride = COUT * NV / 4;
    float4 a = ((const float4*)part)[i];
#pragma unroll
    for (int c = 1; c < NC; ++c) {
        const float4 b = ((const float4*)part)[i + c * stride];
        a.x += b.x; a.y += b.y; a.z += b.z; a.w += b.w;
    }
    ((float4*)y)[i] = a;
}

// ---------------------------------------------------------------------------
// BN stats (training mode, biased var): one block per channel.
// ---------------------------------------------------------------------------
__global__ __launch_bounds__(1024) void bn_stats_kernel(
    const float* __restrict__ y, const float* __restrict__ gamma,
    const float* __restrict__ beta, float* __restrict__ sc, float* __restrict__ sh)
{
    const int c = blockIdx.x;
    const float* yc = y + c * NV;
    float s = 0.0f, s2 = 0.0f;
    for (int i = threadIdx.x; i < NV; i += 1024) {
        const float t = yc[i];
        s += t;
        s2 += t * t;
    }
    __shared__ float ls[1024], ls2[1024];
    ls[threadIdx.x] = s;
    ls2[threadIdx.x] = s2;
    __syncthreads();
    for (int st = 512; st > 0; st >>= 1) {
        if (threadIdx.x < st) {
            ls[threadIdx.x] += ls[threadIdx.x + st];
            ls2[threadIdx.x] += ls2[threadIdx.x + st];
        }
        __syncthreads();
    }
    if (threadIdx.x == 0) {
        const float mu = ls[0] * (1.0f / NV);
        const float var = ls2[0] * (1.0f / NV) - mu * mu;
        const float inv = rsqrtf(var + 1e-5f);
        sc[c] = gamma[c] * inv;
        sh[c] = beta[c] - mu * gamma[c] * inv;
    }
}

__global__ __launch_bounds__(256) void bn_apply_kernel(
    const float* __restrict__ y, const float* __restrict__ sc,
    const float* __restrict__ sh, float* __restrict__ out)
{
    const int i = blockIdx.x * 256 + threadIdx.x;        // float4 index
    const int c = (i * 4) / NV;                          // NV % 4 == 0
    const float a = sc[c], b = sh[c];
    float4 t = ((const float4*)y)[i];
    t.x = fmaxf(t.x * a + b, 0.0f);
    t.y = fmaxf(t.y * a + b, 0.0f);
    t.z = fmaxf(t.z * a + b, 0.0f);
    t.w = fmaxf(t.w * a + b, 0.0f);
    ((float4*)out)[i] = t;
}

// ---------------------------------------------------------------------------
extern "C" void kernel_launch(void* const* d_in, const int* in_sizes, int n_in,
                              void* d_out, int out_size, void* d_ws, size_t ws_size,
                              hipStream_t stream) {
    (void)in_sizes; (void)n_in; (void)out_size; (void)ws_size;

    const float* x      = (const float*)d_in[0];
    const float* w_off1 = (const float*)d_in[1];
    const float* b_off1 = (const float*)d_in[2];
    const float* w1     = (const float*)d_in[3];
    const float* gamma1 = (const float*)d_in[4];
    const float* beta1  = (const float*)d_in[5];
    const float* w_off2 = (const float*)d_in[6];
    const float* b_off2 = (const float*)d_in[7];
    const float* w2     = (const float*)d_in[8];
    const float* gamma2 = (const float*)d_in[9];
    const float* beta2  = (const float*)d_in[10];

    char* ws = (char*)d_ws;
    h16*   off  = (h16*)ws;                 ws += (size_t)81 * NV * sizeof(h16);
    float* y    = (float*)ws;               ws += (size_t)32 * NV * sizeof(float);
    float* h    = (float*)ws;               ws += (size_t)32 * NV * sizeof(float);
    float* part = (float*)ws;               ws += (size_t)4 * 32 * NV * sizeof(float);
    float* sc   = (float*)ws;               ws += 32 * sizeof(float);
    float* sh   = (float*)ws;               ws += 32 * sizeof(float);
    float* wT1  = (float*)ws;               ws += (size_t)27 * 16 * 81 * sizeof(float);
    float* wT2  = (float*)ws;               ws += (size_t)27 * 32 * 81 * sizeof(float);
    float* wD1  = (float*)ws;               ws += (size_t)27 * 16 * 32 * sizeof(float);
    float* wD2  = (float*)ws;               ws += (size_t)27 * 32 * 32 * sizeof(float);

    const int nvb = NV / 256;                 // 432
    const int nel4 = (COUT * NV) / 4 / 256;   // 3456 blocks (float4 grids)
    const int ntile = 432;                    // 12 * 6 * 6

    // ---- weight transposes (tiny) ----
    transpose_w_kernel<<<(81 * 16 * 27 + 255) / 256, 256, 0, stream>>>(w_off1, wT1, 81, 16);
    transpose_w_kernel<<<(81 * 32 * 27 + 255) / 256, 256, 0, stream>>>(w_off2, wT2, 81, 32);
    transpose_w_kernel<<<(32 * 16 * 27 + 255) / 256, 256, 0, stream>>>(w1, wD1, 32, 16);
    transpose_w_kernel<<<(32 * 32 * 27 + 255) / 256, 256, 0, stream>>>(w2, wD2, 32, 32);

    // ---- layer 1 ----
    conv3_off_kernel<16><<<nvb, 256, 0, stream>>>(x, wT1, b_off1, off);
    deform_tile_kernel<16><<<dim3(ntile, 2), 256, 0, stream>>>(x, off, wD1, part);
    reduceN_kernel<2><<<nel4, 256, 0, stream>>>(part, y);
    bn_stats_kernel<<<32, 1024, 0, stream>>>(y, gamma1, beta1, sc, sh);
    bn_apply_kernel<<<nel4, 256, 0, stream>>>(y, sc, sh, h);

    // ---- layer 2 ----
    conv3_off_kernel<32><<<nvb, 256, 0, stream>>>(h, wT2, b_off2, off);
    deform_tile_kernel<32><<<dim3(ntile, 4), 256, 0, stream>>>(h, off, wD2, part);
    reduceN_kernel<4><<<nel4, 256, 0, stream>>>(part, y);
    bn_stats_kernel<<<32, 1024, 0, stream>>>(y, gamma2, beta2, sc, sh);
    bn_apply_kernel<<<nel4, 256, 0, stream>>>(y, sc, sh, (float*)d_out);
}

// Round 6
// 762.427 us; speedup vs baseline: 1.2877x; 1.2877x over previous
//
#include <hip/hip_runtime.h>

#define DD 48
#define HW (48 * 48)
#define NV (48 * 48 * 48)   // 110592 voxels
#define COUT 32

// deform tile geometry
#define TD 4
#define TH 8
#define TW 8
#define RD (TD + 4)         // 8   (halo +-2)
#define RH (TH + 4)         // 12
#define RW (TW + 4)         // 12
#define REGN (RD * RH * RW) // 1152 floats per channel
#define NCH 8               // channels staged per chunk

typedef _Float16 h16;

// ---------------------------------------------------------------------------
// Weight transpose: wt[co][ci][tap] -> wT[tap][ci][co]  (co contiguous so the
// wave-uniform scalar loads in the conv kernels hit 1-2 scalar-cache lines).
// ---------------------------------------------------------------------------
__global__ __launch_bounds__(256) void transpose_w_kernel(
    const float* __restrict__ wt, float* __restrict__ wT, int COUTN, int CIN)
{
    const int i = blockIdx.x * 256 + threadIdx.x;
    const int total = COUTN * CIN * 27;
    if (i >= total) return;
    const int co = i / (CIN * 27);
    const int r = i % (CIN * 27);
    const int ci = r / 27;
    const int tap = r % 27;
    wT[(tap * CIN + ci) * COUTN + co] = wt[i];
}

// ---------------------------------------------------------------------------
// 3x3x3 SAME conv (zero pad), 81 offset channels chunked 27 per blockIdx.y
// (acc[27] fits registers; acc[81] spilled — R4 lesson). ci unrolled x4 so 4
// independent loads issue together and 108 FMAs hide their L2 latency.
// Output fp16.
// ---------------------------------------------------------------------------
template <int CIN>
__global__ __launch_bounds__(256) void conv3_off_kernel(
    const float* __restrict__ x, const float* __restrict__ wT,
    const float* __restrict__ bias, h16* __restrict__ out)
{
    const int v = blockIdx.x * 256 + threadIdx.x;
    const int co0 = blockIdx.y * 27;
    const int d = v / HW;
    const int rem = v % HW;
    const int h = rem / DD;
    const int wv = rem % DD;

    float acc[27];
#pragma unroll
    for (int i = 0; i < 27; ++i) acc[i] = bias[co0 + i];

    int tap = 0;
    for (int dz = -1; dz <= 1; ++dz)
    for (int dy = -1; dy <= 1; ++dy)
    for (int dx = -1; dx <= 1; ++dx, ++tap) {
        const int zd = d + dz, zh = h + dy, zw = wv + dx;
        const bool ok = ((unsigned)zd < 48u) & ((unsigned)zh < 48u) & ((unsigned)zw < 48u);
        if (ok) {
            const int base = (zd * DD + zh) * DD + zw;
            const float* wrow = wT + (tap * CIN) * 81 + co0;
            for (int ci = 0; ci < CIN; ci += 4) {
                const float xv0 = x[(ci + 0) * NV + base];
                const float xv1 = x[(ci + 1) * NV + base];
                const float xv2 = x[(ci + 2) * NV + base];
                const float xv3 = x[(ci + 3) * NV + base];
                const float* wp0 = wrow + (ci + 0) * 81;
                const float* wp1 = wrow + (ci + 1) * 81;
                const float* wp2 = wrow + (ci + 2) * 81;
                const float* wp3 = wrow + (ci + 3) * 81;
#pragma unroll
                for (int i = 0; i < 27; ++i)
                    acc[i] += xv0 * wp0[i] + xv1 * wp1[i]
                            + xv2 * wp2[i] + xv3 * wp3[i];
            }
        }
    }
#pragma unroll
    for (int i = 0; i < 27; ++i) out[(co0 + i) * NV + v] = (h16)acc[i];
}

// ---------------------------------------------------------------------------
// Deformable conv, LDS-tiled. When a coordinate clamps, its trilinear
// fraction is 0, so the +1-neighbor coefficient is 0 -> LDS path reads the 8
// corners at FIXED offsets (compiler merges to ds_read2_b32). Halo values are
// clamp-valid floats, so zero-weighted neighbors are finite.
// ---------------------------------------------------------------------------
template <int CIN>
__global__ __launch_bounds__(256) void deform_tile_kernel(
    const float* __restrict__ x, const h16* __restrict__ off,
    const float* __restrict__ wD, float* __restrict__ part)
{
    __shared__ float reg[NCH][REGN];   // 36864 B

    const int t = threadIdx.x;
    const int bx = blockIdx.x;               // 432 tiles
    const int tilew = bx % 6;
    const int tileh = (bx / 6) % 6;
    const int tiled = bx / 36;               // 0..11
    const int chunk = blockIdx.y;
    const int c0 = chunk * NCH;

    const int tz = t >> 6, ty = (t >> 3) & 7, tx = t & 7;
    const int d  = tiled * TD + tz;
    const int hh = tileh * TH + ty;
    const int ww = tilew * TW + tx;
    const int v  = (d * DD + hh) * DD + ww;

    const int dlo = tiled * TD - 2;
    const int hlo = tileh * TH - 2;
    const int wlo = tilew * TW - 2;

    // ---- stage x region for NCH channels (halo clamped to volume) ----
    for (int i = t; i < NCH * REGN; i += 256) {
        const int ci = i / REGN;
        const int r  = i % REGN;
        const int rz = r / (RH * RW);
        const int rr = r % (RH * RW);
        const int ry = rr / RW, rx = rr % RW;
        const int gz = min(max(dlo + rz, 0), 47);
        const int gy = min(max(hlo + ry, 0), 47);
        const int gx = min(max(wlo + rx, 0), 47);
        reg[ci][r] = x[(c0 + ci) * NV + (gz * DD + gy) * DD + gx];
    }
    __syncthreads();

    float acc[COUT];
#pragma unroll
    for (int i = 0; i < COUT; ++i) acc[i] = 0.0f;

    for (int k = 0; k < 27; ++k) {
        const int dz = k / 9 - 1;
        const int dy = (k / 3) % 3 - 1;
        const int dx = k % 3 - 1;

        const float od = (float)off[(0 * 27 + k) * NV + v];
        const float oh = (float)off[(1 * 27 + k) * NV + v];
        const float ow = (float)off[(2 * 27 + k) * NV + v];

        const float pd = fminf(fmaxf((float)(d + dz) + od, 0.0f), 47.0f);
        const float ph = fminf(fmaxf((float)(hh + dy) + oh, 0.0f), 47.0f);
        const float pw = fminf(fmaxf((float)(ww + dx) + ow, 0.0f), 47.0f);

        const float d0f = floorf(pd), h0f = floorf(ph), w0f = floorf(pw);
        const float fd = pd - d0f, fh = ph - h0f, fw = pw - w0f;
        const int d0 = (int)d0f, h0 = (int)h0f, w0 = (int)w0f;

        const float gd = 1.0f - fd, gh = 1.0f - fh, gw = 1.0f - fw;
        const float c000 = gd * gh * gw, c001 = gd * gh * fw;
        const float c010 = gd * fh * gw, c011 = gd * fh * fw;
        const float c100 = fd * gh * gw, c101 = fd * gh * fw;
        const float c110 = fd * fh * gw, c111 = fd * fh * fw;

        const float* wrow = wD + (k * CIN + c0) * COUT;

        const int ld = d0 - dlo, lh = h0 - hlo, lw = w0 - wlo;
        // fixed-offset reads need ld+1/lh+1/lw+1 in range
        const bool inreg = (ld >= 0) & (ld <= RD - 2)
                         & (lh >= 0) & (lh <= RH - 2)
                         & (lw >= 0) & (lw <= RW - 2);

        if (inreg) {
            const int base = (ld * RH + lh) * RW + lw;
#pragma unroll
            for (int ci = 0; ci < NCH; ++ci) {
                const float* xc = &reg[ci][base];
                const float v000 = xc[0],            v001 = xc[1];
                const float v010 = xc[RW],           v011 = xc[RW + 1];
                const float v100 = xc[RH * RW],      v101 = xc[RH * RW + 1];
                const float v110 = xc[RH * RW + RW], v111 = xc[RH * RW + RW + 1];
                const float val = v000 * c000 + v001 * c001
                                + v010 * c010 + v011 * c011
                                + v100 * c100 + v101 * c101
                                + v110 * c110 + v111 * c111;
                const float* wp = wrow + ci * COUT;
#pragma unroll
                for (int co = 0; co < COUT; ++co)
                    acc[co] += val * wp[co];
            }
        } else {
            const int dst = (d0 < 47) ? 1 : 0;
            const int hst = (h0 < 47) ? 1 : 0;
            const int wst = (w0 < 47) ? 1 : 0;
            const int i000 = (d0 * DD + h0) * DD + w0;
            const int sd = dst ? HW : 0, sh = hst ? DD : 0, sw = wst;
#pragma unroll
            for (int ci = 0; ci < NCH; ++ci) {
                const float* xc = x + (c0 + ci) * NV + i000;
                const float val = xc[0]       * c000 + xc[sw]           * c001
                                + xc[sh]      * c010 + xc[sh + sw]      * c011
                                + xc[sd]      * c100 + xc[sd + sw]      * c101
                                + xc[sd + sh] * c110 + xc[sd + sh + sw] * c111;
                const float* wp = wrow + ci * COUT;
#pragma unroll
                for (int co = 0; co < COUT; ++co)
                    acc[co] += val * wp[co];
            }
        }
    }

#pragma unroll
    for (int co = 0; co < COUT; ++co)
        part[(chunk * COUT + co) * NV + v] = acc[co];
}

// Sum NC split-K partials (float4).
template <int NC>
__global__ __launch_bounds__(256) void reduceN_kernel(
    const float* __restrict__ part, float* __restrict__ y)
{
    const int i = blockIdx.x * 256 + threadIdx.x;   // float4 index
    const int stride = COUT * NV / 4;
    float4 a = ((const float4*)part)[i];
#pragma unroll
    for (int c = 1; c < NC; ++c) {
        const float4 b = ((const float4*)part)[i + c * stride];
        a.x += b.x; a.y += b.y; a.z += b.z; a.w += b.w;
    }
    ((float4*)y)[i] = a;
}

// ---------------------------------------------------------------------------
// BN stats, two-stage: stage 1 = grid (32 ch, 8 parts), each block reduces
// NV/8 elements (float4) -> partial (sum, sumsq). Stage 2 = 1 tiny block
// combines and emits fused scale/shift.
// ---------------------------------------------------------------------------
__global__ __launch_bounds__(256) void bn_stats_part_kernel(
    const float* __restrict__ y, float* __restrict__ pbuf)
{
    const int c = blockIdx.x, p = blockIdx.y;
    const float4* yc4 = (const float4*)(y + c * NV);
    const int chunk4 = NV / 4 / 8;           // 3456
    float s = 0.0f, s2 = 0.0f;
    for (int i = p * chunk4 + threadIdx.x; i < (p + 1) * chunk4; i += 256) {
        const float4 t = yc4[i];
        s  += t.x + t.y + t.z + t.w;
        s2 += t.x * t.x + t.y * t.y + t.z * t.z + t.w * t.w;
    }
    __shared__ float ls[256], ls2[256];
    ls[threadIdx.x] = s; ls2[threadIdx.x] = s2;
    __syncthreads();
    for (int st = 128; st > 0; st >>= 1) {
        if (threadIdx.x < st) {
            ls[threadIdx.x]  += ls[threadIdx.x + st];
            ls2[threadIdx.x] += ls2[threadIdx.x + st];
        }
        __syncthreads();
    }
    if (threadIdx.x == 0) {
        pbuf[(c * 8 + p) * 2 + 0] = ls[0];
        pbuf[(c * 8 + p) * 2 + 1] = ls2[0];
    }
}

__global__ __launch_bounds__(64) void bn_stats_final_kernel(
    const float* __restrict__ pbuf, const float* __restrict__ gamma,
    const float* __restrict__ beta, float* __restrict__ sc, float* __restrict__ sh)
{
    const int c = threadIdx.x;
    if (c >= 32) return;
    float s = 0.0f, s2 = 0.0f;
#pragma unroll
    for (int p = 0; p < 8; ++p) {
        s  += pbuf[(c * 8 + p) * 2 + 0];
        s2 += pbuf[(c * 8 + p) * 2 + 1];
    }
    const float mu = s * (1.0f / NV);
    const float var = s2 * (1.0f / NV) - mu * mu;
    const float inv = rsqrtf(var + 1e-5f);
    sc[c] = gamma[c] * inv;
    sh[c] = beta[c] - mu * gamma[c] * inv;
}

__global__ __launch_bounds__(256) void bn_apply_kernel(
    const float* __restrict__ y, const float* __restrict__ sc,
    const float* __restrict__ sh, float* __restrict__ out)
{
    const int i = blockIdx.x * 256 + threadIdx.x;        // float4 index
    const int c = (i * 4) / NV;                          // NV % 4 == 0
    const float a = sc[c], b = sh[c];
    float4 t = ((const float4*)y)[i];
    t.x = fmaxf(t.x * a + b, 0.0f);
    t.y = fmaxf(t.y * a + b, 0.0f);
    t.z = fmaxf(t.z * a + b, 0.0f);
    t.w = fmaxf(t.w * a + b, 0.0f);
    ((float4*)out)[i] = t;
}

// ---------------------------------------------------------------------------
extern "C" void kernel_launch(void* const* d_in, const int* in_sizes, int n_in,
                              void* d_out, int out_size, void* d_ws, size_t ws_size,
                              hipStream_t stream) {
    (void)in_sizes; (void)n_in; (void)out_size; (void)ws_size;

    const float* x      = (const float*)d_in[0];
    const float* w_off1 = (const float*)d_in[1];
    const float* b_off1 = (const float*)d_in[2];
    const float* w1     = (const float*)d_in[3];
    const float* gamma1 = (const float*)d_in[4];
    const float* beta1  = (const float*)d_in[5];
    const float* w_off2 = (const float*)d_in[6];
    const float* b_off2 = (const float*)d_in[7];
    const float* w2     = (const float*)d_in[8];
    const float* gamma2 = (const float*)d_in[9];
    const float* beta2  = (const float*)d_in[10];

    char* ws = (char*)d_ws;
    h16*   off  = (h16*)ws;                 ws += (size_t)81 * NV * sizeof(h16);
    float* y    = (float*)ws;               ws += (size_t)32 * NV * sizeof(float);
    float* h    = (float*)ws;               ws += (size_t)32 * NV * sizeof(float);
    float* part = (float*)ws;               ws += (size_t)4 * 32 * NV * sizeof(float);
    float* sc   = (float*)ws;               ws += 32 * sizeof(float);
    float* sh   = (float*)ws;               ws += 32 * sizeof(float);
    float* pbuf = (float*)ws;               ws += 32 * 8 * 2 * sizeof(float);
    float* wT1  = (float*)ws;               ws += (size_t)27 * 16 * 81 * sizeof(float);
    float* wT2  = (float*)ws;               ws += (size_t)27 * 32 * 81 * sizeof(float);
    float* wD1  = (float*)ws;               ws += (size_t)27 * 16 * 32 * sizeof(float);
    float* wD2  = (float*)ws;               ws += (size_t)27 * 32 * 32 * sizeof(float);

    const int nvb = NV / 256;                 // 432
    const int nel4 = (COUT * NV) / 4 / 256;   // 3456 blocks (float4 grids)
    const int ntile = 432;                    // 12 * 6 * 6

    // ---- weight transposes (tiny) ----
    transpose_w_kernel<<<(81 * 16 * 27 + 255) / 256, 256, 0, stream>>>(w_off1, wT1, 81, 16);
    transpose_w_kernel<<<(81 * 32 * 27 + 255) / 256, 256, 0, stream>>>(w_off2, wT2, 81, 32);
    transpose_w_kernel<<<(32 * 16 * 27 + 255) / 256, 256, 0, stream>>>(w1, wD1, 32, 16);
    transpose_w_kernel<<<(32 * 32 * 27 + 255) / 256, 256, 0, stream>>>(w2, wD2, 32, 32);

    // ---- layer 1 ----
    conv3_off_kernel<16><<<dim3(nvb, 3), 256, 0, stream>>>(x, wT1, b_off1, off);
    deform_tile_kernel<16><<<dim3(ntile, 2), 256, 0, stream>>>(x, off, wD1, part);
    reduceN_kernel<2><<<nel4, 256, 0, stream>>>(part, y);
    bn_stats_part_kernel<<<dim3(32, 8), 256, 0, stream>>>(y, pbuf);
    bn_stats_final_kernel<<<1, 64, 0, stream>>>(pbuf, gamma1, beta1, sc, sh);
    bn_apply_kernel<<<nel4, 256, 0, stream>>>(y, sc, sh, h);

    // ---- layer 2 ----
    conv3_off_kernel<32><<<dim3(nvb, 3), 256, 0, stream>>>(h, wT2, b_off2, off);
    deform_tile_kernel<32><<<dim3(ntile, 4), 256, 0, stream>>>(h, off, wD2, part);
    reduceN_kernel<4><<<nel4, 256, 0, stream>>>(part, y);
    bn_stats_part_kernel<<<dim3(32, 8), 256, 0, stream>>>(y, pbuf);
    bn_stats_final_kernel<<<1, 64, 0, stream>>>(pbuf, gamma2, beta2, sc, sh);
    bn_apply_kernel<<<nel4, 256, 0, stream>>>(y, sc, sh, (float*)d_out);
}

// Round 7
// 566.825 us; speedup vs baseline: 1.7320x; 1.3451x over previous
//
#include <hip/hip_runtime.h>

#define DD 48
#define HW (48 * 48)
#define NV (48 * 48 * 48)   // 110592 voxels
#define COUT 32

// deform tile geometry
#define TD 4
#define TH 8
#define TW 8
#define RD (TD + 4)         // 8   (halo +-2)
#define RH (TH + 4)         // 12
#define RW (TW + 4)         // 12
#define REGN (RD * RH * RW) // 1152 floats per channel
#define NCH 8               // channels staged per chunk

typedef _Float16 h16;
typedef __attribute__((ext_vector_type(8))) short bf16x8;
typedef __attribute__((ext_vector_type(4))) float f32x4;
typedef __attribute__((ext_vector_type(4))) int i32x4;

__device__ __forceinline__ unsigned int bf16rne(float f) {
    unsigned int u = __builtin_bit_cast(unsigned int, f);
    return (u + 0x7FFFu + ((u >> 16) & 1u)) >> 16;
}

// ---------------------------------------------------------------------------
// W_pre for the MFMA offset conv: bf16 [m=96][kpad], k = tap*CIN + ci,
// zero-padded in m (81..95) and k (>=27*CIN).
// ---------------------------------------------------------------------------
template <int CIN>
__global__ __launch_bounds__(256) void make_wpre_kernel(
    const float* __restrict__ w, unsigned short* __restrict__ Wp)
{
    constexpr int NCHUNK = (CIN == 32) ? 27 : 14;
    constexpr int KPAD = NCHUNK * 32;
    const int i = blockIdx.x * 256 + threadIdx.x;
    if (i >= 96 * KPAD) return;
    const int m = i / KPAD;
    const int kg = i % KPAD;
    const int tap = kg / CIN, ci = kg % CIN;
    float val = 0.f;
    if (m < 81 && tap < 27) val = w[m * (CIN * 27) + ci * 27 + tap];
    Wp[i] = (unsigned short)bf16rne(val);
}

// Weight transpose for deform: wt[co][ci][tap] -> wT[tap][ci][co].
__global__ __launch_bounds__(256) void transpose_w_kernel(
    const float* __restrict__ wt, float* __restrict__ wT, int COUTN, int CIN)
{
    const int i = blockIdx.x * 256 + threadIdx.x;
    const int total = COUTN * CIN * 27;
    if (i >= total) return;
    const int co = i / (CIN * 27);
    const int r = i % (CIN * 27);
    const int ci = r / 27;
    const int tap = r % 27;
    wT[(tap * CIN + ci) * COUTN + co] = wt[i];
}

// ---------------------------------------------------------------------------
// Offset conv as MFMA GEMM: out[96(81), NV] = W[96, K] * im2col(x)[K, NV].
// Block = 96 x 128 output tile, 4 waves (each: all 96 rows x 32 cols).
// Per K-chunk(32): stage X-tile bf16 into LDS (swizzled [kpair][n] words:
// word(k,n) = (k>>1)*128 + ((n + 8*(k>>3)) & 127); both write and read are
// 2-way bank aliased = free), A-fragments read straight from W_pre (L2).
// ---------------------------------------------------------------------------
template <int CIN>
__global__ __launch_bounds__(256) void conv_off_mfma_kernel(
    const float* __restrict__ x, const unsigned short* __restrict__ Wp,
    const float* __restrict__ bias, h16* __restrict__ out)
{
    constexpr int NCHUNK = (CIN == 32) ? 27 : 14;
    constexpr int KPAD = NCHUNK * 32;
    __shared__ unsigned int lds[16 * 128];   // 8 KB

    const int t = threadIdx.x;
    const int v0 = blockIdx.x * 128;

    // staging assignment: voxel n = t>>1, k-half = t&1 (16 k each)
    const int sn = t >> 1;
    const int skh = t & 1;
    const int sv = v0 + sn;
    const int sd = sv / HW;
    const int shh = (sv / DD) % DD;
    const int sww = sv % DD;

    // wave/lane decomposition for MFMA
    const int wv = t >> 6;
    const int l = t & 63;
    const int lg = l >> 4;      // 0..3
    const int ln = l & 15;

    // B-read swizzled n-part for the wave's two n-subtiles
    const int bw0 = (((2 * wv) * 16 + ln) + 8 * lg) & 127;
    const int bw1 = (((2 * wv + 1) * 16 + ln) + 8 * lg) & 127;

    // A lane base (bf16 elements)
    const int abase = ln * KPAD + lg * 8;

    f32x4 acc[6][2];
#pragma unroll
    for (int r = 0; r < 6; ++r)
#pragma unroll
        for (int nt = 0; nt < 2; ++nt)
            acc[r][nt] = (f32x4){0.f, 0.f, 0.f, 0.f};

    for (int c = 0; c < NCHUNK; ++c) {
        __syncthreads();   // previous chunk's reads done
        {
            const int kg0 = c * 32 + skh * 16;
            const int tap = kg0 / CIN;        // uniform per thread
            unsigned int pk[8];
            if (tap < 27) {
                const int dz = tap / 9 - 1;
                const int dy = (tap / 3) % 3 - 1;
                const int dx = tap % 3 - 1;
                const int zd = sd + dz, zh = shh + dy, zw = sww + dx;
                const bool ok = ((unsigned)zd < 48u) & ((unsigned)zh < 48u)
                              & ((unsigned)zw < 48u);
                const int gbase = (zd * DD + zh) * DD + zw;
                const int ci0 = kg0 % CIN;
                const float* xb = x + ci0 * NV + gbase;
#pragma unroll
                for (int p = 0; p < 8; ++p) {
                    const float f0 = ok ? xb[(2 * p) * NV] : 0.f;
                    const float f1 = ok ? xb[(2 * p + 1) * NV] : 0.f;
                    pk[p] = bf16rne(f0) | (bf16rne(f1) << 16);
                }
            } else {
#pragma unroll
                for (int p = 0; p < 8; ++p) pk[p] = 0u;
            }
#pragma unroll
            for (int p = 0; p < 8; ++p) {
                const int word = (skh * 8 + p) * 128
                               + ((sn + 16 * skh + 8 * (p >> 2)) & 127);
                lds[word] = pk[p];
            }
        }
        __syncthreads();

        const unsigned short* wp = Wp + c * 32 + abase;
#pragma unroll
        for (int r = 0; r < 6; ++r) {
            const bf16x8 a = *(const bf16x8*)(wp + r * 16 * KPAD);
#pragma unroll
            for (int nt = 0; nt < 2; ++nt) {
                const int bw = nt ? bw1 : bw0;
                const int w0 = (int)lds[(4 * lg + 0) * 128 + bw];
                const int w1 = (int)lds[(4 * lg + 1) * 128 + bw];
                const int w2 = (int)lds[(4 * lg + 2) * 128 + bw];
                const int w3 = (int)lds[(4 * lg + 3) * 128 + bw];
                const i32x4 wi = {w0, w1, w2, w3};
                const bf16x8 b = __builtin_bit_cast(bf16x8, wi);
                acc[r][nt] = __builtin_amdgcn_mfma_f32_16x16x32_bf16(a, b, acc[r][nt], 0, 0, 0);
            }
        }
    }

    // epilogue: D layout col=l&15, row=(l>>4)*4+reg
#pragma unroll
    for (int r = 0; r < 6; ++r) {
        const int mbase = r * 16 + lg * 4;
#pragma unroll
        for (int j = 0; j < 4; ++j) {
            const int m = mbase + j;
            if (m < 81) {
#pragma unroll
                for (int nt = 0; nt < 2; ++nt) {
                    const int col = v0 + (2 * wv + nt) * 16 + ln;
                    out[m * NV + col] = (h16)(acc[r][nt][j] + bias[m]);
                }
            }
        }
    }
}

// ---------------------------------------------------------------------------
// Deformable conv, LDS-tiled (unchanged from R5 base).
// ---------------------------------------------------------------------------
template <int CIN>
__global__ __launch_bounds__(256) void deform_tile_kernel(
    const float* __restrict__ x, const h16* __restrict__ off,
    const float* __restrict__ wD, float* __restrict__ part)
{
    __shared__ float reg[NCH][REGN];   // 36864 B

    const int t = threadIdx.x;
    const int bx = blockIdx.x;               // 432 tiles
    const int tilew = bx % 6;
    const int tileh = (bx / 6) % 6;
    const int tiled = bx / 36;               // 0..11
    const int chunk = blockIdx.y;
    const int c0 = chunk * NCH;

    const int tz = t >> 6, ty = (t >> 3) & 7, tx = t & 7;
    const int d  = tiled * TD + tz;
    const int hh = tileh * TH + ty;
    const int ww = tilew * TW + tx;
    const int v  = (d * DD + hh) * DD + ww;

    const int dlo = tiled * TD - 2;
    const int hlo = tileh * TH - 2;
    const int wlo = tilew * TW - 2;

    for (int i = t; i < NCH * REGN; i += 256) {
        const int ci = i / REGN;
        const int r  = i % REGN;
        const int rz = r / (RH * RW);
        const int rr = r % (RH * RW);
        const int ry = rr / RW, rx = rr % RW;
        const int gz = min(max(dlo + rz, 0), 47);
        const int gy = min(max(hlo + ry, 0), 47);
        const int gx = min(max(wlo + rx, 0), 47);
        reg[ci][r] = x[(c0 + ci) * NV + (gz * DD + gy) * DD + gx];
    }
    __syncthreads();

    float acc[COUT];
#pragma unroll
    for (int i = 0; i < COUT; ++i) acc[i] = 0.0f;

    for (int k = 0; k < 27; ++k) {
        const int dz = k / 9 - 1;
        const int dy = (k / 3) % 3 - 1;
        const int dx = k % 3 - 1;

        const float od = (float)off[(0 * 27 + k) * NV + v];
        const float oh = (float)off[(1 * 27 + k) * NV + v];
        const float ow = (float)off[(2 * 27 + k) * NV + v];

        const float pd = fminf(fmaxf((float)(d + dz) + od, 0.0f), 47.0f);
        const float ph = fminf(fmaxf((float)(hh + dy) + oh, 0.0f), 47.0f);
        const float pw = fminf(fmaxf((float)(ww + dx) + ow, 0.0f), 47.0f);

        const float d0f = floorf(pd), h0f = floorf(ph), w0f = floorf(pw);
        const float fd = pd - d0f, fh = ph - h0f, fw = pw - w0f;
        const int d0 = (int)d0f, h0 = (int)h0f, w0 = (int)w0f;

        const float gd = 1.0f - fd, gh = 1.0f - fh, gw = 1.0f - fw;
        const float c000 = gd * gh * gw, c001 = gd * gh * fw;
        const float c010 = gd * fh * gw, c011 = gd * fh * fw;
        const float c100 = fd * gh * gw, c101 = fd * gh * fw;
        const float c110 = fd * fh * gw, c111 = fd * fh * fw;

        const float* wrow = wD + (k * CIN + c0) * COUT;

        const int ld = d0 - dlo, lh = h0 - hlo, lw = w0 - wlo;
        const bool inreg = (ld >= 0) & (ld <= RD - 2)
                         & (lh >= 0) & (lh <= RH - 2)
                         & (lw >= 0) & (lw <= RW - 2);

        if (inreg) {
            const int base = (ld * RH + lh) * RW + lw;
#pragma unroll
            for (int ci = 0; ci < NCH; ++ci) {
                const float* xc = &reg[ci][base];
                const float v000 = xc[0],            v001 = xc[1];
                const float v010 = xc[RW],           v011 = xc[RW + 1];
                const float v100 = xc[RH * RW],      v101 = xc[RH * RW + 1];
                const float v110 = xc[RH * RW + RW], v111 = xc[RH * RW + RW + 1];
                const float val = v000 * c000 + v001 * c001
                                + v010 * c010 + v011 * c011
                                + v100 * c100 + v101 * c101
                                + v110 * c110 + v111 * c111;
                const float* wpp = wrow + ci * COUT;
#pragma unroll
                for (int co = 0; co < COUT; ++co)
                    acc[co] += val * wpp[co];
            }
        } else {
            const int dst = (d0 < 47) ? 1 : 0;
            const int hst = (h0 < 47) ? 1 : 0;
            const int wst = (w0 < 47) ? 1 : 0;
            const int i000 = (d0 * DD + h0) * DD + w0;
            const int sd2 = dst ? HW : 0, sh2 = hst ? DD : 0, sw2 = wst;
#pragma unroll
            for (int ci = 0; ci < NCH; ++ci) {
                const float* xc = x + (c0 + ci) * NV + i000;
                const float val = xc[0]         * c000 + xc[sw2]             * c001
                                + xc[sh2]       * c010 + xc[sh2 + sw2]       * c011
                                + xc[sd2]       * c100 + xc[sd2 + sw2]       * c101
                                + xc[sd2 + sh2] * c110 + xc[sd2 + sh2 + sw2] * c111;
                const float* wpp = wrow + ci * COUT;
#pragma unroll
                for (int co = 0; co < COUT; ++co)
                    acc[co] += val * wpp[co];
            }
        }
    }

#pragma unroll
    for (int co = 0; co < COUT; ++co)
        part[(chunk * COUT + co) * NV + v] = acc[co];
}

// Sum NC split-K partials (float4).
template <int NC>
__global__ __launch_bounds__(256) void reduceN_kernel(
    const float* __restrict__ part, float* __restrict__ y)
{
    const int i = blockIdx.x * 256 + threadIdx.x;
    const int stride = COUT * NV / 4;
    float4 a = ((const float4*)part)[i];
#pragma unroll
    for (int c = 1; c < NC; ++c) {
        const float4 b = ((const float4*)part)[i + c * stride];
        a.x += b.x; a.y += b.y; a.z += b.z; a.w += b.w;
    }
    ((float4*)y)[i] = a;
}

// BN stats two-stage.
__global__ __launch_bounds__(256) void bn_stats_part_kernel(
    const float* __restrict__ y, float* __restrict__ pbuf)
{
    const int c = blockIdx.x, p = blockIdx.y;
    const float4* yc4 = (const float4*)(y + c * NV);
    const int chunk4 = NV / 4 / 8;           // 3456
    float s = 0.0f, s2 = 0.0f;
    for (int i = p * chunk4 + threadIdx.x; i < (p + 1) * chunk4; i += 256) {
        const float4 t = yc4[i];
        s  += t.x + t.y + t.z + t.w;
        s2 += t.x * t.x + t.y * t.y + t.z * t.z + t.w * t.w;
    }
    __shared__ float ls[256], ls2[256];
    ls[threadIdx.x] = s; ls2[threadIdx.x] = s2;
    __syncthreads();
    for (int st = 128; st > 0; st >>= 1) {
        if (threadIdx.x < st) {
            ls[threadIdx.x]  += ls[threadIdx.x + st];
            ls2[threadIdx.x] += ls2[threadIdx.x + st];
        }
        __syncthreads();
    }
    if (threadIdx.x == 0) {
        pbuf[(c * 8 + p) * 2 + 0] = ls[0];
        pbuf[(c * 8 + p) * 2 + 1] = ls2[0];
    }
}

__global__ __launch_bounds__(64) void bn_stats_final_kernel(
    const float* __restrict__ pbuf, const float* __restrict__ gamma,
    const float* __restrict__ beta, float* __restrict__ sc, float* __restrict__ sh)
{
    const int c = threadIdx.x;
    if (c >= 32) return;
    float s = 0.0f, s2 = 0.0f;
#pragma unroll
    for (int p = 0; p < 8; ++p) {
        s  += pbuf[(c * 8 + p) * 2 + 0];
        s2 += pbuf[(c * 8 + p) * 2 + 1];
    }
    const float mu = s * (1.0f / NV);
    const float var = s2 * (1.0f / NV) - mu * mu;
    const float inv = rsqrtf(var + 1e-5f);
    sc[c] = gamma[c] * inv;
    sh[c] = beta[c] - mu * gamma[c] * inv;
}

__global__ __launch_bounds__(256) void bn_apply_kernel(
    const float* __restrict__ y, const float* __restrict__ sc,
    const float* __restrict__ sh, float* __restrict__ out)
{
    const int i = blockIdx.x * 256 + threadIdx.x;
    const int c = (i * 4) / NV;
    const float a = sc[c], b = sh[c];
    float4 t = ((const float4*)y)[i];
    t.x = fmaxf(t.x * a + b, 0.0f);
    t.y = fmaxf(t.y * a + b, 0.0f);
    t.z = fmaxf(t.z * a + b, 0.0f);
    t.w = fmaxf(t.w * a + b, 0.0f);
    ((float4*)out)[i] = t;
}

// ---------------------------------------------------------------------------
extern "C" void kernel_launch(void* const* d_in, const int* in_sizes, int n_in,
                              void* d_out, int out_size, void* d_ws, size_t ws_size,
                              hipStream_t stream) {
    (void)in_sizes; (void)n_in; (void)out_size; (void)ws_size;

    const float* x      = (const float*)d_in[0];
    const float* w_off1 = (const float*)d_in[1];
    const float* b_off1 = (const float*)d_in[2];
    const float* w1     = (const float*)d_in[3];
    const float* gamma1 = (const float*)d_in[4];
    const float* beta1  = (const float*)d_in[5];
    const float* w_off2 = (const float*)d_in[6];
    const float* b_off2 = (const float*)d_in[7];
    const float* w2     = (const float*)d_in[8];
    const float* gamma2 = (const float*)d_in[9];
    const float* beta2  = (const float*)d_in[10];

    char* ws = (char*)d_ws;
    h16*   off  = (h16*)ws;                 ws += (size_t)81 * NV * sizeof(h16);
    float* y    = (float*)ws;               ws += (size_t)32 * NV * sizeof(float);
    float* h    = (float*)ws;               ws += (size_t)32 * NV * sizeof(float);
    float* part = (float*)ws;               ws += (size_t)4 * 32 * NV * sizeof(float);
    float* sc   = (float*)ws;               ws += 32 * sizeof(float);
    float* sh   = (float*)ws;               ws += 32 * sizeof(float);
    float* pbuf = (float*)ws;               ws += 32 * 8 * 2 * sizeof(float);
    unsigned short* Wp1 = (unsigned short*)ws; ws += (size_t)96 * 448 * sizeof(unsigned short);
    unsigned short* Wp2 = (unsigned short*)ws; ws += (size_t)96 * 864 * sizeof(unsigned short);
    float* wD1  = (float*)ws;               ws += (size_t)27 * 16 * 32 * sizeof(float);
    float* wD2  = (float*)ws;               ws += (size_t)27 * 32 * 32 * sizeof(float);

    const int nel4 = (COUT * NV) / 4 / 256;   // 3456 blocks (float4 grids)
    const int ntile = 432;                    // 12 * 6 * 6
    const int ngemm = NV / 128;               // 864

    // ---- weight prep (tiny) ----
    make_wpre_kernel<16><<<(96 * 448 + 255) / 256, 256, 0, stream>>>(w_off1, Wp1);
    make_wpre_kernel<32><<<(96 * 864 + 255) / 256, 256, 0, stream>>>(w_off2, Wp2);
    transpose_w_kernel<<<(32 * 16 * 27 + 255) / 256, 256, 0, stream>>>(w1, wD1, 32, 16);
    transpose_w_kernel<<<(32 * 32 * 27 + 255) / 256, 256, 0, stream>>>(w2, wD2, 32, 32);

    // ---- layer 1 ----
    conv_off_mfma_kernel<16><<<ngemm, 256, 0, stream>>>(x, Wp1, b_off1, off);
    deform_tile_kernel<16><<<dim3(ntile, 2), 256, 0, stream>>>(x, off, wD1, part);
    reduceN_kernel<2><<<nel4, 256, 0, stream>>>(part, y);
    bn_stats_part_kernel<<<dim3(32, 8), 256, 0, stream>>>(y, pbuf);
    bn_stats_final_kernel<<<1, 64, 0, stream>>>(pbuf, gamma1, beta1, sc, sh);
    bn_apply_kernel<<<nel4, 256, 0, stream>>>(y, sc, sh, h);

    // ---- layer 2 ----
    conv_off_mfma_kernel<32><<<ngemm, 256, 0, stream>>>(h, Wp2, b_off2, off);
    deform_tile_kernel<32><<<dim3(ntile, 4), 256, 0, stream>>>(h, off, wD2, part);
    reduceN_kernel<4><<<nel4, 256, 0, stream>>>(part, y);
    bn_stats_part_kernel<<<dim3(32, 8), 256, 0, stream>>>(y, pbuf);
    bn_stats_final_kernel<<<1, 64, 0, stream>>>(pbuf, gamma2, beta2, sc, sh);
    bn_apply_kernel<<<nel4, 256, 0, stream>>>(y, sc, sh, (float*)d_out);
}